// Round 5
// baseline (271.602 us; speedup 1.0000x reference)
//
#include <hip/hip_runtime.h>

typedef __bf16 bx8 __attribute__((ext_vector_type(8)));
typedef __bf16 bx4 __attribute__((ext_vector_type(4)));
typedef float  fx4 __attribute__((ext_vector_type(4)));
typedef unsigned long long u64;

#define B_   4
#define S_   2048
#define DIN  1024
#define DH   1024

#define MB ((size_t)1 << 20)
// workspace layout (bytes)
#define WS_A1 ((size_t)0)          // seq1 bf16, 16MB   (aliased by Pu later)
#define WS_A2 ((size_t)16*MB)      // seq2 bf16, 16MB   (aliased by Pu later)
#define WS_PU ((size_t)0)          // exp-scores bf16, 32MB (after QKV done)
#define WS_WQ ((size_t)32*MB)      // Wq bf16 2MB; after Q-proj reused as mask bitmask (2MB)
#define WS_BM WS_WQ
#define WS_WK ((size_t)34*MB)      // Wk,Wv contiguous => fused [Wk;Wv] N=2048
#define WS_WV ((size_t)36*MB)
#define WS_Q  ((size_t)38*MB)      // q bf16 [B*S, DH] 16MB
#define WS_K  ((size_t)54*MB)      // k bf16 [B*S, DH] 16MB
#define WS_VT ((size_t)70*MB)      // v^T bf16 [B, DH, S] 16MB
#define WS_CS ((size_t)86*MB)      // colsum fp32 [B, S] 32KB

// ---------------------------------------------------------------- cvt f32->bf16
__global__ void cvt_f32_bf16(const float* __restrict__ in, __bf16* __restrict__ out) {
  size_t i = (size_t)blockIdx.x * blockDim.x + threadIdx.x;
  fx4 lo = ((const fx4*)in)[2 * i];
  fx4 hi = ((const fx4*)in)[2 * i + 1];
  bx8 o;
#pragma unroll
  for (int j = 0; j < 4; j++) { o[j] = (__bf16)lo[j]; o[j + 4] = (__bf16)hi[j]; }
  ((bx8*)out)[i] = o;
}

// ---------------------------------------------------------------- pack int32 mask -> bits
__global__ void pack_mask(const int* __restrict__ m, u64* __restrict__ w) {
  const int wid = threadIdx.x >> 6, lane = threadIdx.x & 63;
  const size_t base = ((size_t)blockIdx.x * 4 + wid) * 512;
#pragma unroll
  for (int i = 0; i < 8; i++) {
    int v = m[base + i * 64 + lane];
    u64 b = __ballot(v != 0);
    if (lane == 0) w[base / 64 + i] = b;
  }
}

// ---------------------------------------------------------------- 256x256 GEMM  C = A @ B^T
// BM=BN=256, BK=64, 512 thr = 8 waves (2 wr x 4 wc), per-wave 128x64, acc[8][4].
// LDS 128KB: buf*65536 + {A: [256][128B] at 0, B: [256][128B] at 32768}.
// Swizzle: lds colb = logical_colb ^ ((row&7)<<4); inverse folded into global src.
// R3-proven 8-barrier schedule: per phase {ds_reads + 2 GLD, BAR, setprio MFMA16
// setprio, BAR}; ENDSYNC = vmcnt(4)+barrier once per K-tile.
// Phases (balanced reads 8/8/4/4): ph0 kk0/m0-3, ph1 kk1/m0-3, ph2 kk0/m4-7,
// ph3 kk1/m4-7. Staging: ph0/ph1 -> A(t+1) halves (buf nb); ph2/ph3 -> B(t+2)
// halves (buf cb; cb-B dead after ph1's reads, guarded by ph1's two barriers).
// vmcnt(4) at tile end retires {B(t+1),A(t+1)}, keeps B(t+2)'s 4 in flight.

enum { EP_BF16 = 0, EP_KV = 1, EP_EXP = 2, EP_F32 = 3 };

#define GLD(gp, lp)                                                              \
  __builtin_amdgcn_global_load_lds(                                              \
      (const __attribute__((address_space(1))) void*)(const void*)(gp),          \
      (__attribute__((address_space(3))) void*)(void*)(lp), 16, 0, 0)

#define BARS()                                   \
  do {                                           \
    asm volatile("" ::: "memory");               \
    __builtin_amdgcn_s_barrier();                \
    __builtin_amdgcn_sched_barrier(0);           \
  } while (0)

#define ENDSYNC()                                          \
  do {                                                     \
    asm volatile("s_waitcnt vmcnt(4)" ::: "memory");       \
    __builtin_amdgcn_s_barrier();                          \
    __builtin_amdgcn_sched_barrier(0);                     \
  } while (0)

#define MM(m, n, av, bv) \
  acc[m][n] = __builtin_amdgcn_mfma_f32_16x16x32_bf16(av, bv, acc[m][n], 0, 0, 0)
#define MFMA16X(mA, mB, mC, mD, b0_, b1_, b2_, b3_) do {                          \
  MM(mA,0,am0,b0_); MM(mA,1,am0,b1_); MM(mA,2,am0,b2_); MM(mA,3,am0,b3_);         \
  MM(mB,0,am1,b0_); MM(mB,1,am1,b1_); MM(mB,2,am1,b2_); MM(mB,3,am1,b3_);         \
  MM(mC,0,am2,b0_); MM(mC,1,am2,b1_); MM(mC,2,am2,b2_); MM(mC,3,am2,b3_);         \
  MM(mD,0,am3,b0_); MM(mD,1,am3,b1_); MM(mD,2,am3,b2_); MM(mD,3,am3,b3_);         \
} while (0)

#define LDA_(buf, m, kk) (*(const bx8*)(aBase + (buf) * 65536 + (m) * 2048 + ((kk) ? c1s : c0s)))
#define LDB_(buf, n, kk) (*(const bx8*)(bBase + (buf) * 65536 + (n) * 2048 + ((kk) ? c1s : c0s)))
#define RD_A4(buf, mb, kk)                                        \
  am0 = LDA_(buf, (mb) + 0, kk); am1 = LDA_(buf, (mb) + 1, kk);   \
  am2 = LDA_(buf, (mb) + 2, kk); am3 = LDA_(buf, (mb) + 3, kk)

#define STAGE_A(kt, h, buf) do {                                                          \
  GLD(pA + (size_t)((h) * 128) * K + (kt),      smem + (buf) * 65536 + (h) * 16384 + tid * 16);        \
  GLD(pA + (size_t)((h) * 128 + 64) * K + (kt), smem + (buf) * 65536 + (h) * 16384 + 8192 + tid * 16); \
} while (0)
#define STAGE_B(kt, h, buf) do {                                                          \
  GLD(pB + (size_t)((h) * 128) * K + (kt),      smem + (buf) * 65536 + 32768 + (h) * 16384 + tid * 16);        \
  GLD(pB + (size_t)((h) * 128 + 64) * K + (kt), smem + (buf) * 65536 + 32768 + (h) * 16384 + 8192 + tid * 16); \
} while (0)

template <int EPI, int SPLIT>
__global__ __launch_bounds__(512, 2) void gemm256(
    const __bf16* __restrict__ A, const __bf16* __restrict__ Bm,
    void* __restrict__ Cout, void* __restrict__ Cout2,
    const u64* __restrict__ MaskW, int N, int K, int KE, long sA, long sB) {
  extern __shared__ char smem[];

  // ---- XCD-aware bijective swizzle (all grids are multiples of 8 blocks)
  const unsigned gx = gridDim.x, gy = gridDim.y;
  const unsigned nwg = gx * gy * gridDim.z;
  unsigned flat = (blockIdx.z * gy + blockIdx.y) * gx + blockIdx.x;
  flat = (flat & 7) * (nwg >> 3) + (flat >> 3);
  const int lx = __builtin_ctz(gx), ly = __builtin_ctz(gy);
  const int bxi = flat & (gx - 1);
  const int byi = (flat >> lx) & (gy - 1);
  int bz = flat >> (lx + ly);

  if (SPLIT) {
    const int half = bz & 1;
    bz >>= 1;
    A  += (long)bz * sA + half * KE;
    Bm += (long)bz * sB + half * KE;
  } else {
    A  += (long)bz * sA;
    Bm += (long)bz * sB;
  }
  const int brow = byi * 256;
  const int bcol = bxi * 256;

  const int tid  = threadIdx.x;
  const int wid  = tid >> 6;
  const int lane = tid & 63;
  const int wr = wid >> 2;   // 0..1 -> rows wr*128
  const int wc = wid & 3;    // 0..3 -> cols wc*64

  fx4 acc[8][4] = {};

  // staging: thread covers lds flat tid*16 (+8192*i) per half; inverse swizzle on global col
  const int gcol = (((tid & 7) ^ ((tid >> 3) & 7)) << 3);  // elements
  const __bf16* pA = A  + (size_t)(brow + (tid >> 3)) * K + gcol;
  const __bf16* pB = Bm + (size_t)(bcol + (tid >> 3)) * K + gcol;

  // fragment read bases (read-side swizzle)
  const int frow = lane & 15;
  const int slot = (lane >> 4) << 4;
  const int c0s  = slot ^ ((frow & 7) << 4);
  const int c1s  = (64 + slot) ^ ((frow & 7) << 4);
  const char* aBase = smem + (wr * 128 + frow) * 128;
  const char* bBase = smem + 32768 + (wc * 64 + frow) * 128;

  // ---- prologue: tile0 fully + B halves of tile1; keep 4 loads in flight
  STAGE_A(0, 0, 0); STAGE_A(0, 1, 0);
  STAGE_B(0, 0, 0); STAGE_B(0, 1, 0);
  STAGE_B(64, 0, 1); STAGE_B(64, 1, 1);
  ENDSYNC();

  const int nt = KE >> 6;
  bx8 am0, am1, am2, am3;
  bx8 bk0n0, bk0n1, bk0n2, bk0n3, bk1n0, bk1n1, bk1n2, bk1n3;

  for (int t = 0; t < nt; ++t) {
    const int cb = t & 1, nb = cb ^ 1;
    const int kA = (t + 1 < nt) ? (t + 1) * 64 : 0;  // junk when past end, never read
    const int kB = (t + 2 < nt) ? (t + 2) * 64 : 0;

    // ---- ph0: kk0, m0-3 (8 ds_reads)
    RD_A4(cb, 0, 0);
    bk0n0 = LDB_(cb, 0, 0); bk0n1 = LDB_(cb, 1, 0); bk0n2 = LDB_(cb, 2, 0); bk0n3 = LDB_(cb, 3, 0);
    STAGE_A(kA, 0, nb);
    BARS();
    __builtin_amdgcn_s_setprio(1); MFMA16X(0, 1, 2, 3, bk0n0, bk0n1, bk0n2, bk0n3); __builtin_amdgcn_s_setprio(0);
    BARS();
    // ---- ph1: kk1, m0-3 (8 ds_reads)
    RD_A4(cb, 0, 1);
    bk1n0 = LDB_(cb, 0, 1); bk1n1 = LDB_(cb, 1, 1); bk1n2 = LDB_(cb, 2, 1); bk1n3 = LDB_(cb, 3, 1);
    STAGE_A(kA, 1, nb);
    BARS();
    __builtin_amdgcn_s_setprio(1); MFMA16X(0, 1, 2, 3, bk1n0, bk1n1, bk1n2, bk1n3); __builtin_amdgcn_s_setprio(0);
    BARS();
    // ---- ph2: kk0, m4-7 (4 ds_reads; cb-B dead -> stage B(t+2) half0 there)
    RD_A4(cb, 4, 0);
    STAGE_B(kB, 0, cb);
    BARS();
    __builtin_amdgcn_s_setprio(1); MFMA16X(4, 5, 6, 7, bk0n0, bk0n1, bk0n2, bk0n3); __builtin_amdgcn_s_setprio(0);
    BARS();
    // ---- ph3: kk1, m4-7
    RD_A4(cb, 4, 1);
    STAGE_B(kB, 1, cb);
    BARS();
    __builtin_amdgcn_s_setprio(1); MFMA16X(4, 5, 6, 7, bk1n0, bk1n1, bk1n2, bk1n3); __builtin_amdgcn_s_setprio(0);
    ENDSYNC();  // retires {B(t+1), A(t+1)}; keeps B(t+2) (4 loads) in flight
  }

  // ---- epilogue: C/D layout col = lane&15, row = (lane>>4)*4 + j  [verified m89]
  const int r0 = wr * 128 + (lane >> 4) * 4;
  const int c0 = wc * 64 + (lane & 15);

  if (EPI == EP_BF16) {
    __bf16* C = (__bf16*)Cout;
#pragma unroll
    for (int m = 0; m < 8; m++) {
      int row = brow + r0 + m * 16;
#pragma unroll
      for (int n = 0; n < 4; n++) {
        int col = bcol + c0 + n * 16;
#pragma unroll
        for (int j = 0; j < 4; j++)
          C[(size_t)(row + j) * N + col] = (__bf16)acc[m][n][j];
      }
    }
  } else if (EPI == EP_KV) {
    // cols 0-1023 -> k [8192,1024]; cols 1024-2047 -> vT[b][col-1024][s]
    __bf16* Ck = (__bf16*)Cout;
    __bf16* Cv = (__bf16*)Cout2;
    if (bcol < 1024) {
#pragma unroll
      for (int m = 0; m < 8; m++) {
        int row = brow + r0 + m * 16;
#pragma unroll
        for (int n = 0; n < 4; n++) {
          int col = bcol + c0 + n * 16;
#pragma unroll
          for (int j = 0; j < 4; j++)
            Ck[(size_t)(row + j) * 1024 + col] = (__bf16)acc[m][n][j];
        }
      }
    } else {
#pragma unroll
      for (int m = 0; m < 8; m++) {
        int row  = brow + r0 + m * 16;
        size_t bb = (size_t)(row >> 11) << 21;  // batch * DH*S
        int sidx = row & 2047;
#pragma unroll
        for (int n = 0; n < 4; n++) {
          int col = bcol + c0 + n * 16 - 1024;
          bx4 tv;
#pragma unroll
          for (int j = 0; j < 4; j++) tv[j] = (__bf16)acc[m][n][j];
          *(bx4*)&Cv[bb + (size_t)col * S_ + sidx] = tv;
        }
      }
    }
  } else if (EPI == EP_EXP) {
    __bf16* C    = (__bf16*)Cout + (size_t)bz * ((size_t)S_ * S_);
    const u64* Wm = MaskW + (((size_t)bz * S_ * S_) >> 6);
    float* cs    = (float*)Cout2 + (size_t)bz * S_;
#pragma unroll
    for (int n = 0; n < 4; n++) {
      int col = bcol + c0 + n * 16;
      float csum = 0.f;
#pragma unroll
      for (int m = 0; m < 8; m++) {
        int row = brow + r0 + m * 16;
#pragma unroll
        for (int j = 0; j < 4; j++) {
          size_t idx = (size_t)(row + j) * S_ + col;
          bool mk = (Wm[idx >> 6] >> (idx & 63)) & 1;
          float p = mk ? 1.0f : __expf(acc[m][n][j] * 0.03125f);  // 1/sqrt(1024)
          csum += p;
          C[idx] = (__bf16)p;
        }
      }
      atomicAdd(&cs[col], csum);
    }
  } else {  // EP_F32 (+SPLIT: atomic accumulate of K-halves)
    float* C = (float*)Cout + (size_t)bz * ((size_t)S_ * DH);
#pragma unroll
    for (int m = 0; m < 8; m++) {
      int row = brow + r0 + m * 16;
#pragma unroll
      for (int n = 0; n < 4; n++) {
        int col = bcol + c0 + n * 16;
#pragma unroll
        for (int j = 0; j < 4; j++) {
          if (SPLIT) atomicAdd(&C[(size_t)(row + j) * N + col], acc[m][n][j]);
          else       C[(size_t)(row + j) * N + col] = acc[m][n][j];
        }
      }
    }
  }
}

// ---------------------------------------------------------------- vT[b][h][k] /= colsum[b][k]
__global__ void scale_vt(__bf16* __restrict__ vT, const float* __restrict__ cs) {
  size_t i = (size_t)blockIdx.x * blockDim.x + threadIdx.x;
  size_t e = i * 8;
  int b = (int)(e >> 21);      // DH*S = 2^21 elems per batch
  int k = (int)(e & (S_ - 1)); // contiguous along k
  bx8 v = ((bx8*)vT)[i];
  const float* c = cs + (size_t)b * S_ + k;
#pragma unroll
  for (int j = 0; j < 8; j++) v[j] = (__bf16)((float)v[j] / c[j]);
  ((bx8*)vT)[i] = v;
}

// ---------------------------------------------------------------- launch
extern "C" void kernel_launch(void* const* d_in, const int* in_sizes, int n_in,
                              void* d_out, int out_size, void* d_ws, size_t ws_size,
                              hipStream_t stream) {
  const float* seq1 = (const float*)d_in[0];
  const float* seq2 = (const float*)d_in[1];
  const int*   mask = (const int*)d_in[2];
  const float* Wq   = (const float*)d_in[3];
  const float* Wk   = (const float*)d_in[4];
  const float* Wv   = (const float*)d_in[5];

  char* ws = (char*)d_ws;
  __bf16* A1  = (__bf16*)(ws + WS_A1);
  __bf16* A2  = (__bf16*)(ws + WS_A2);
  __bf16* Pu  = (__bf16*)(ws + WS_PU);
  __bf16* WQb = (__bf16*)(ws + WS_WQ);
  u64*    bm  = (u64*)(ws + WS_BM);      // aliases WQb after Q-proj
  __bf16* WKb = (__bf16*)(ws + WS_WK);   // [Wk;Wv] contiguous 2048x1024
  __bf16* WVb = (__bf16*)(ws + WS_WV);
  __bf16* qb  = (__bf16*)(ws + WS_Q);
  __bf16* kb  = (__bf16*)(ws + WS_K);
  __bf16* vTb = (__bf16*)(ws + WS_VT);
  float*  cs  = (float*)(ws + WS_CS);

  (void)hipFuncSetAttribute((const void*)gemm256<EP_BF16, 0>,
      hipFuncAttributeMaxDynamicSharedMemorySize, 131072);
  (void)hipFuncSetAttribute((const void*)gemm256<EP_KV, 0>,
      hipFuncAttributeMaxDynamicSharedMemorySize, 131072);
  (void)hipFuncSetAttribute((const void*)gemm256<EP_EXP, 0>,
      hipFuncAttributeMaxDynamicSharedMemorySize, 131072);
  (void)hipFuncSetAttribute((const void*)gemm256<EP_F32, 1>,
      hipFuncAttributeMaxDynamicSharedMemorySize, 131072);

  // fp32 -> bf16 conversions
  cvt_f32_bf16<<<4096, 256, 0, stream>>>(seq1, A1);
  cvt_f32_bf16<<<4096, 256, 0, stream>>>(seq2, A2);
  cvt_f32_bf16<<<512, 256, 0, stream>>>(Wq, WQb);
  cvt_f32_bf16<<<512, 256, 0, stream>>>(Wk, WKb);
  cvt_f32_bf16<<<512, 256, 0, stream>>>(Wv, WVb);

  // q = seq1 @ Wq^T   (M=8192, N=1024)
  gemm256<EP_BF16, 0><<<dim3(DH / 256, (B_ * S_) / 256, 1), 512, 131072, stream>>>(
      A1, WQb, qb, nullptr, nullptr, DH, DIN, DIN, 0, 0);
  // [k | vT] = seq2 @ [Wk;Wv]^T  (M=8192, N=2048, split epilogue)
  gemm256<EP_KV, 0><<<dim3(2048 / 256, (B_ * S_) / 256, 1), 512, 131072, stream>>>(
      A2, WKb, kb, vTb, nullptr, 2048, DIN, DIN, 0, 0);

  // pack mask to bits (overwrites Wq region, dead after Q-proj)
  pack_mask<<<8192, 256, 0, stream>>>(mask, bm);
  hipMemsetAsync(ws + WS_CS, 0, (size_t)B_ * S_ * sizeof(float), stream);

  // Pu[b,q,k] = mask ? 1 : exp(q.k/32); fused fp32 column-sum atomics into cs
  gemm256<EP_EXP, 0><<<dim3(S_ / 256, S_ / 256, B_), 512, 131072, stream>>>(
      qb, kb, Pu, cs, bm, S_, DH, DH, (long)S_ * DH, (long)S_ * DH);

  // fold 1/colsum into vT
  scale_vt<<<(B_ * DH * S_ / 8) / 256, 256, 0, stream>>>(vTb, cs);

  // out[b,q,h] = sum_k Pu[b,q,k] * vT'[b,h,k]   (M=2048, N=1024, K=2048, split-K x2)
  hipMemsetAsync(d_out, 0, (size_t)B_ * S_ * DH * sizeof(float), stream);
  gemm256<EP_F32, 1><<<dim3(DH / 256, S_ / 256, B_ * 2), 512, 131072, stream>>>(
      Pu, vTb, (float*)d_out, nullptr, nullptr, DH, S_, S_ / 2, (long)S_ * S_, (long)DH * S_);
}

// Round 6
// 223.645 us; speedup vs baseline: 1.2144x; 1.2144x over previous
//
#include <hip/hip_runtime.h>

typedef __bf16 bx8 __attribute__((ext_vector_type(8)));
typedef __bf16 bx4 __attribute__((ext_vector_type(4)));
typedef float  fx4 __attribute__((ext_vector_type(4)));
typedef unsigned long long u64;

#define B_   4
#define S_   2048
#define DIN  1024
#define DH   1024

#define MB ((size_t)1 << 20)
// workspace layout (bytes)
#define WS_A1 ((size_t)0)          // seq1 bf16, 16MB  (stacked with A2; aliased by Pu later)
#define WS_A2 ((size_t)16*MB)      // seq2 bf16, 16MB  (A1..A2 contiguous = 16384x1024)
#define WS_PU ((size_t)0)          // exp-scores bf16, 32MB (after QKV done)
#define WS_WQ ((size_t)32*MB)      // Wq bf16 2MB  (WQ..WK..WV contiguous)
#define WS_WK ((size_t)34*MB)
#define WS_WV ((size_t)36*MB)
#define WS_BM ((size_t)38*MB)      // mask bitmask 2MB (before qb)... see WS_Q shift
#define WS_Q  ((size_t)40*MB)      // q bf16 [B*S, DH] 16MB
#define WS_K  ((size_t)56*MB)      // k bf16 [B*S, DH] 16MB
#define WS_VT ((size_t)72*MB)      // v^T bf16 [B, DH, S] 16MB
#define WS_CS ((size_t)88*MB)      // colsum fp32 [B, S] 32KB

// ---------------------------------------------------------------- cvt f32->bf16 (2 arrays)
__global__ void cvt_seq(const float* __restrict__ s1, const float* __restrict__ s2,
                        __bf16* __restrict__ o1, __bf16* __restrict__ o2) {
  const float* in  = blockIdx.y ? s2 : s1;
  __bf16*      out = blockIdx.y ? o2 : o1;
  size_t i = (size_t)blockIdx.x * blockDim.x + threadIdx.x;
  fx4 lo = ((const fx4*)in)[2 * i];
  fx4 hi = ((const fx4*)in)[2 * i + 1];
  bx8 o;
#pragma unroll
  for (int j = 0; j < 4; j++) { o[j] = (__bf16)lo[j]; o[j + 4] = (__bf16)hi[j]; }
  ((bx8*)out)[i] = o;
}
__global__ void cvt_w(const float* __restrict__ wq, const float* __restrict__ wk,
                      const float* __restrict__ wv, __bf16* __restrict__ oq) {
  const float* in = blockIdx.y == 0 ? wq : (blockIdx.y == 1 ? wk : wv);
  __bf16* out = oq + (size_t)blockIdx.y * (DH * DIN);  // WQ,WK,WV contiguous
  size_t i = (size_t)blockIdx.x * blockDim.x + threadIdx.x;
  fx4 lo = ((const fx4*)in)[2 * i];
  fx4 hi = ((const fx4*)in)[2 * i + 1];
  bx8 o;
#pragma unroll
  for (int j = 0; j < 4; j++) { o[j] = (__bf16)lo[j]; o[j + 4] = (__bf16)hi[j]; }
  ((bx8*)out)[i] = o;
}

// ---------------------------------------------------------------- pack int32 mask -> bits
__global__ void pack_mask(const int* __restrict__ m, u64* __restrict__ w) {
  const int wid = threadIdx.x >> 6, lane = threadIdx.x & 63;
  const size_t base = ((size_t)blockIdx.x * 4 + wid) * 512;
#pragma unroll
  for (int i = 0; i < 8; i++) {
    int v = m[base + i * 64 + lane];
    u64 b = __ballot(v != 0);
    if (lane == 0) w[base / 64 + i] = b;
  }
}

// ---------------------------------------------------------------- 256x256 GEMM  C = A @ B^T
// R3-proven structure: BM=BN=256, BK=64, 8 waves (2x4), per-wave 128x64, acc[8][4].
// LDS 128KB: buf*65536 + {A:[256][128B] @0, B:[256][128B] @32768}.
// Swizzle: lds colb = logical_colb ^ ((row&7)<<4); inverse folded into global src.
// Phases 12/4/4/4 reads; per phase {reads + 2 GLD, BAR, setprio MFMA16 setprio, BAR};
// ENDSYNC = vmcnt(4)+barrier per K-tile retires {B(t+1),A(t+1)}, keeps B(t+2) in flight.

enum { EP_QKV = 0, EP_EXP = 2, EP_F32 = 3 };

#define GLD(gp, lp)                                                              \
  __builtin_amdgcn_global_load_lds(                                              \
      (const __attribute__((address_space(1))) void*)(const void*)(gp),          \
      (__attribute__((address_space(3))) void*)(void*)(lp), 16, 0, 0)

#define BARS()                                   \
  do {                                           \
    asm volatile("" ::: "memory");               \
    __builtin_amdgcn_s_barrier();                \
    __builtin_amdgcn_sched_barrier(0);           \
  } while (0)

#define ENDSYNC()                                          \
  do {                                                     \
    asm volatile("s_waitcnt vmcnt(4)" ::: "memory");       \
    __builtin_amdgcn_s_barrier();                          \
    __builtin_amdgcn_sched_barrier(0);                     \
  } while (0)

#define MM(m, n, av, bv) \
  acc[m][n] = __builtin_amdgcn_mfma_f32_16x16x32_bf16(av, bv, acc[m][n], 0, 0, 0)
#define MFMA16(mA, mB) do {                                                       \
  MM(mA,0,a0k0,bk0n0); MM(mA,1,a0k0,bk0n1); MM(mA,2,a0k0,bk0n2); MM(mA,3,a0k0,bk0n3); \
  MM(mB,0,a1k0,bk0n0); MM(mB,1,a1k0,bk0n1); MM(mB,2,a1k0,bk0n2); MM(mB,3,a1k0,bk0n3); \
  MM(mA,0,a0k1,bk1n0); MM(mA,1,a0k1,bk1n1); MM(mA,2,a0k1,bk1n2); MM(mA,3,a0k1,bk1n3); \
  MM(mB,0,a1k1,bk1n0); MM(mB,1,a1k1,bk1n1); MM(mB,2,a1k1,bk1n2); MM(mB,3,a1k1,bk1n3); \
} while (0)

#define LDA_(buf, m, kk) (*(const bx8*)(aBase + (buf) * 65536 + (m) * 2048 + ((kk) ? c1s : c0s)))
#define LDB_(buf, n, kk) (*(const bx8*)(bBase + (buf) * 65536 + (n) * 2048 + ((kk) ? c1s : c0s)))
#define RD_A(cb, mA, mB)                             \
  a0k0 = LDA_(cb, mA, 0); a0k1 = LDA_(cb, mA, 1);    \
  a1k0 = LDA_(cb, mB, 0); a1k1 = LDA_(cb, mB, 1)

#define STAGE_A(kt, h, buf) do {                                                          \
  GLD(pA + (size_t)((h) * 128) * K + (kt),      smem + (buf) * 65536 + (h) * 16384 + tid * 16);        \
  GLD(pA + (size_t)((h) * 128 + 64) * K + (kt), smem + (buf) * 65536 + (h) * 16384 + 8192 + tid * 16); \
} while (0)
#define STAGE_B(kt, h, buf) do {                                                          \
  GLD(pB + (size_t)((h) * 128) * K + (kt),      smem + (buf) * 65536 + 32768 + (h) * 16384 + tid * 16);        \
  GLD(pB + (size_t)((h) * 128 + 64) * K + (kt), smem + (buf) * 65536 + 32768 + (h) * 16384 + 8192 + tid * 16); \
} while (0)

template <int EPI>
__global__ __launch_bounds__(512, 2) void gemm256(
    const __bf16* __restrict__ A, const __bf16* __restrict__ Bm,
    void* __restrict__ Cout, void* __restrict__ Cout2,
    const void* __restrict__ Xtra, int N, int K, long sA, long sB) {
  extern __shared__ char smem[];

  int brow, bcol, bz = 0;
  bool isQ = false;
  if (EPI == EP_QKV) {
    // 384 blocks 1D: f<128 -> Q (4 col-blocks x 32 row-blocks of stacked A rows 0-8191);
    // f>=128 -> KV (8 col-blocks x 32 row-blocks of rows 8192-16383). XCD swizzle chunk=48.
    int f = (blockIdx.x & 7) * 48 + (blockIdx.x >> 3);
    if (f < 128) {
      isQ = true;
      brow = (f >> 2) * 256;
      bcol = (f & 3) * 256;
    } else {
      int g = f - 128;
      brow = 8192 + (g >> 3) * 256;
      bcol = (g & 7) * 256;
    }
  } else {
    // XCD-aware bijective swizzle (pow2 grids, nwg % 8 == 0)
    const unsigned gx = gridDim.x, gy = gridDim.y;
    const unsigned nwg = gx * gy * gridDim.z;
    unsigned flat = (blockIdx.z * gy + blockIdx.y) * gx + blockIdx.x;
    flat = (flat & 7) * (nwg >> 3) + (flat >> 3);
    const int lx = __builtin_ctz(gx), ly = __builtin_ctz(gy);
    brow = ((flat >> lx) & (gy - 1)) * 256;
    bcol = (flat & (gx - 1)) * 256;
    bz   = flat >> (lx + ly);
    A  += (long)bz * sA;
    Bm += (long)bz * sB;
  }

  const int tid  = threadIdx.x;
  const int wid  = tid >> 6;
  const int lane = tid & 63;
  const int wr = wid >> 2;   // 0..1 -> rows wr*128
  const int wc = wid & 3;    // 0..3 -> cols wc*64

  fx4 acc[8][4] = {};

  // staging: thread covers lds flat tid*16 (+8192*i) per half; inverse swizzle on global col
  const int gcol = (((tid & 7) ^ ((tid >> 3) & 7)) << 3);  // elements
  const __bf16* Bsel = (EPI == EP_QKV && !isQ) ? (Bm + (size_t)1048576) : Bm;  // WK follows WQ
  const __bf16* pA = A    + (size_t)(brow + (tid >> 3)) * K + gcol;
  const __bf16* pB = Bsel + (size_t)(bcol + (tid >> 3)) * K + gcol;

  // fragment read bases (read-side swizzle)
  const int frow = lane & 15;
  const int slot = (lane >> 4) << 4;
  const int c0s  = slot ^ ((frow & 7) << 4);
  const int c1s  = (64 + slot) ^ ((frow & 7) << 4);
  const char* aBase = smem + (wr * 128 + frow) * 128;
  const char* bBase = smem + 32768 + (wc * 64 + frow) * 128;

  // ---- prologue: tile0 fully + B halves of tile1; keep 4 loads in flight
  STAGE_A(0, 0, 0); STAGE_A(0, 1, 0);
  STAGE_B(0, 0, 0); STAGE_B(0, 1, 0);
  STAGE_B(64, 0, 1); STAGE_B(64, 1, 1);
  ENDSYNC();

  const int nt = K >> 6;
  bx8 a0k0, a0k1, a1k0, a1k1;
  bx8 bk0n0, bk0n1, bk0n2, bk0n3, bk1n0, bk1n1, bk1n2, bk1n3;

  for (int t = 0; t < nt; ++t) {
    const int cb = t & 1, nb = cb ^ 1;
    const int kA = (t + 1 < nt) ? (t + 1) * 64 : 0;  // junk when past end, never read
    const int kB = (t + 2 < nt) ? (t + 2) * 64 : 0;

    // ---- ph0: m0,m1 (12 ds_reads: 4 A + 8 B; B regs held all tile)
    RD_A(cb, 0, 1);
    bk0n0 = LDB_(cb, 0, 0); bk0n1 = LDB_(cb, 1, 0); bk0n2 = LDB_(cb, 2, 0); bk0n3 = LDB_(cb, 3, 0);
    bk1n0 = LDB_(cb, 0, 1); bk1n1 = LDB_(cb, 1, 1); bk1n2 = LDB_(cb, 2, 1); bk1n3 = LDB_(cb, 3, 1);
    STAGE_A(kA, 0, nb);
    BARS();
    __builtin_amdgcn_s_setprio(1); MFMA16(0, 1); __builtin_amdgcn_s_setprio(0);
    BARS();
    // ---- ph1: m2,m3
    RD_A(cb, 2, 3);
    STAGE_A(kA, 1, nb);
    BARS();
    __builtin_amdgcn_s_setprio(1); MFMA16(2, 3); __builtin_amdgcn_s_setprio(0);
    BARS();
    // ---- ph2: m4,m5  (cb-B dead after ph0 -> stage B(t+2) half0 there)
    RD_A(cb, 4, 5);
    STAGE_B(kB, 0, cb);
    BARS();
    __builtin_amdgcn_s_setprio(1); MFMA16(4, 5); __builtin_amdgcn_s_setprio(0);
    BARS();
    // ---- ph3: m6,m7
    RD_A(cb, 6, 7);
    STAGE_B(kB, 1, cb);
    BARS();
    __builtin_amdgcn_s_setprio(1); MFMA16(6, 7); __builtin_amdgcn_s_setprio(0);
    ENDSYNC();  // retires {B(t+1), A(t+1)}; keeps B(t+2) (4 loads) in flight
  }

  // ---- epilogue: C/D layout col = lane&15, row = (lane>>4)*4 + j  [verified m89]
  const int r0 = wr * 128 + (lane >> 4) * 4;
  const int c0 = wc * 64 + (lane & 15);

  if (EPI == EP_QKV) {
    if (isQ) {
      __bf16* Cq = (__bf16*)Cout;
#pragma unroll
      for (int m = 0; m < 8; m++) {
        int row = brow + r0 + m * 16;
#pragma unroll
        for (int n = 0; n < 4; n++) {
          int col = bcol + c0 + n * 16;
#pragma unroll
          for (int j = 0; j < 4; j++)
            Cq[(size_t)(row + j) * 1024 + col] = (__bf16)acc[m][n][j];
        }
      }
    } else {
      __bf16* Ck = (__bf16*)Cout2;
      __bf16* Cv = (__bf16*)Xtra;
      if (bcol < 1024) {
#pragma unroll
        for (int m = 0; m < 8; m++) {
          int rr = brow - 8192 + r0 + m * 16;
#pragma unroll
          for (int n = 0; n < 4; n++) {
            int col = bcol + c0 + n * 16;
#pragma unroll
            for (int j = 0; j < 4; j++)
              Ck[(size_t)(rr + j) * 1024 + col] = (__bf16)acc[m][n][j];
          }
        }
      } else {
#pragma unroll
        for (int m = 0; m < 8; m++) {
          int rr = brow - 8192 + r0 + m * 16;
          size_t bb = (size_t)(rr >> 11) << 21;  // batch * DH*S
          int sidx = rr & 2047;
#pragma unroll
          for (int n = 0; n < 4; n++) {
            int col = bcol + c0 + n * 16 - 1024;
            bx4 tv;
#pragma unroll
            for (int j = 0; j < 4; j++) tv[j] = (__bf16)acc[m][n][j];
            *(bx4*)&Cv[bb + (size_t)col * S_ + sidx] = tv;
          }
        }
      }
    }
  } else if (EPI == EP_EXP) {
    __bf16* C     = (__bf16*)Cout + (size_t)bz * ((size_t)S_ * S_);
    const u64* Wm = (const u64*)Xtra + (((size_t)bz * S_ * S_) >> 6);
#pragma unroll
    for (int m = 0; m < 8; m++) {
      int row = brow + r0 + m * 16;
#pragma unroll
      for (int n = 0; n < 4; n++) {
        int col = bcol + c0 + n * 16;
#pragma unroll
        for (int j = 0; j < 4; j++) {
          size_t idx = (size_t)(row + j) * S_ + col;
          bool mk = (Wm[idx >> 6] >> (idx & 63)) & 1;
          float p = mk ? 1.0f : __expf(acc[m][n][j] * 0.03125f);  // 1/sqrt(1024)
          C[idx] = (__bf16)p;
        }
      }
    }
  } else {  // EP_F32
    float* C = (float*)Cout + (size_t)bz * ((size_t)S_ * DH);
#pragma unroll
    for (int m = 0; m < 8; m++) {
      int row = brow + r0 + m * 16;
#pragma unroll
      for (int n = 0; n < 4; n++) {
        int col = bcol + c0 + n * 16;
#pragma unroll
        for (int j = 0; j < 4; j++)
          C[(size_t)(row + j) * N + col] = acc[m][n][j];
      }
    }
  }
}

// ---------------------------------------------------------------- column sums of Pu
__global__ void colsum_partial(const __bf16* __restrict__ Pu, float* __restrict__ cs) {
  int b  = blockIdx.z;
  int k  = blockIdx.x * 256 + threadIdx.x;
  int q0 = blockIdx.y * 256;
  const __bf16* P = Pu + (size_t)b * S_ * S_ + (size_t)q0 * S_ + k;
  float s = 0.f;
#pragma unroll 8
  for (int q = 0; q < 256; q++) s += (float)P[(size_t)q * S_];
  atomicAdd(&cs[b * S_ + k], s);
}

// ---------------------------------------------------------------- vT[b][h][k] /= colsum[b][k]
__global__ void scale_vt(__bf16* __restrict__ vT, const float* __restrict__ cs) {
  size_t i = (size_t)blockIdx.x * blockDim.x + threadIdx.x;
  size_t e = i * 8;
  int b = (int)(e >> 21);      // DH*S = 2^21 elems per batch
  int k = (int)(e & (S_ - 1)); // contiguous along k
  bx8 v = ((bx8*)vT)[i];
  const float* c = cs + (size_t)b * S_ + k;
#pragma unroll
  for (int j = 0; j < 8; j++) v[j] = (__bf16)((float)v[j] / c[j]);
  ((bx8*)vT)[i] = v;
}

// ---------------------------------------------------------------- launch
extern "C" void kernel_launch(void* const* d_in, const int* in_sizes, int n_in,
                              void* d_out, int out_size, void* d_ws, size_t ws_size,
                              hipStream_t stream) {
  const float* seq1 = (const float*)d_in[0];
  const float* seq2 = (const float*)d_in[1];
  const int*   mask = (const int*)d_in[2];
  const float* Wq   = (const float*)d_in[3];
  const float* Wk   = (const float*)d_in[4];
  const float* Wv   = (const float*)d_in[5];

  char* ws = (char*)d_ws;
  __bf16* A1  = (__bf16*)(ws + WS_A1);   // stacked [seq1;seq2] 16384x1024
  __bf16* A2  = (__bf16*)(ws + WS_A2);
  __bf16* Pu  = (__bf16*)(ws + WS_PU);
  __bf16* WQb = (__bf16*)(ws + WS_WQ);   // WQ,WK,WV contiguous 3072x1024
  u64*    bm  = (u64*)(ws + WS_BM);
  __bf16* qb  = (__bf16*)(ws + WS_Q);
  __bf16* kb  = (__bf16*)(ws + WS_K);
  __bf16* vTb = (__bf16*)(ws + WS_VT);
  float*  cs  = (float*)(ws + WS_CS);

  (void)hipFuncSetAttribute((const void*)gemm256<EP_QKV>,
      hipFuncAttributeMaxDynamicSharedMemorySize, 131072);
  (void)hipFuncSetAttribute((const void*)gemm256<EP_EXP>,
      hipFuncAttributeMaxDynamicSharedMemorySize, 131072);
  (void)hipFuncSetAttribute((const void*)gemm256<EP_F32>,
      hipFuncAttributeMaxDynamicSharedMemorySize, 131072);

  // fp32 -> bf16 conversions (2 launches)
  cvt_seq<<<dim3(4096, 2, 1), 256, 0, stream>>>(seq1, seq2, A1, A2);
  cvt_w<<<dim3(512, 3, 1), 256, 0, stream>>>(Wq, Wk, Wv, WQb);
  // pack mask to bits
  pack_mask<<<8192, 256, 0, stream>>>(mask, bm);
  hipMemsetAsync(ws + WS_CS, 0, (size_t)B_ * S_ * sizeof(float), stream);

  // fused q/k/vT projections: 384 blocks over stacked A
  gemm256<EP_QKV><<<384, 512, 131072, stream>>>(
      A1, WQb, qb, kb, vTb, 0, DIN, 0, 0);

  // Pu[b,q,k] = mask ? 1 : exp(q.k/32)   (overwrites A1/A2, dead now)
  gemm256<EP_EXP><<<dim3(S_ / 256, S_ / 256, B_), 512, 131072, stream>>>(
      qb, kb, Pu, nullptr, bm, S_, DH, (long)S_ * DH, (long)S_ * DH);

  // column sums over q, then fold 1/colsum into vT
  colsum_partial<<<dim3(S_ / 256, S_ / 256, B_), 256, 0, stream>>>(Pu, cs);
  scale_vt<<<(B_ * DH * S_ / 8) / 256, 256, 0, stream>>>(vTb, cs);

  // out[b,q,h] = sum_k Pu[b,q,k] * vT'[b,h,k]   (M=2048, N=1024, K=2048)
  gemm256<EP_F32><<<dim3(DH / 256, S_ / 256, B_), 512, 131072, stream>>>(
      Pu, vTb, (float*)d_out, nullptr, nullptr, DH, S_, (long)S_ * S_, (long)DH * S_);
}

// Round 7
// 208.966 us; speedup vs baseline: 1.2997x; 1.0702x over previous
//
#include <hip/hip_runtime.h>

typedef __bf16 bx8 __attribute__((ext_vector_type(8)));
typedef __bf16 bx4 __attribute__((ext_vector_type(4)));
typedef float  fx4 __attribute__((ext_vector_type(4)));
typedef unsigned long long u64;

#define B_   4
#define S_   2048
#define DIN  1024
#define DH   1024

#define MB ((size_t)1 << 20)
// workspace layout (bytes)
#define WS_A1 ((size_t)0)          // seq1 bf16, 16MB  (stacked with A2; aliased by Pu later)
#define WS_A2 ((size_t)16*MB)      // seq2 bf16, 16MB  (A1..A2 contiguous = 16384x1024)
#define WS_PU ((size_t)0)          // exp-scores bf16, 32MB (after QKV done)
#define WS_WQ ((size_t)32*MB)      // WQ,WK,WV bf16 contiguous 3072x1024 (6MB)
#define WS_BM ((size_t)38*MB)      // mask bitmask 2MB
#define WS_Q  ((size_t)40*MB)      // q bf16 [B*S, DH] 16MB
#define WS_K  ((size_t)56*MB)      // k bf16 [B*S, DH] 16MB
#define WS_VT ((size_t)72*MB)      // v^T bf16 [B, DH, S] 16MB
#define WS_CS ((size_t)88*MB)      // colsum fp32 [B, S] 32KB

// ---------------------------------------------------------------- cvt f32->bf16
__global__ void cvt_seq(const float* __restrict__ s1, const float* __restrict__ s2,
                        __bf16* __restrict__ o1, __bf16* __restrict__ o2) {
  const float* in  = blockIdx.y ? s2 : s1;
  __bf16*      out = blockIdx.y ? o2 : o1;
  size_t i = (size_t)blockIdx.x * blockDim.x + threadIdx.x;
  fx4 lo = ((const fx4*)in)[2 * i];
  fx4 hi = ((const fx4*)in)[2 * i + 1];
  bx8 o;
#pragma unroll
  for (int j = 0; j < 4; j++) { o[j] = (__bf16)lo[j]; o[j + 4] = (__bf16)hi[j]; }
  ((bx8*)out)[i] = o;
}
__global__ void cvt_w(const float* __restrict__ wq, const float* __restrict__ wk,
                      const float* __restrict__ wv, __bf16* __restrict__ oq) {
  const float* in = blockIdx.y == 0 ? wq : (blockIdx.y == 1 ? wk : wv);
  __bf16* out = oq + (size_t)blockIdx.y * (DH * DIN);
  size_t i = (size_t)blockIdx.x * blockDim.x + threadIdx.x;
  fx4 lo = ((const fx4*)in)[2 * i];
  fx4 hi = ((const fx4*)in)[2 * i + 1];
  bx8 o;
#pragma unroll
  for (int j = 0; j < 4; j++) { o[j] = (__bf16)lo[j]; o[j + 4] = (__bf16)hi[j]; }
  ((bx8*)out)[i] = o;
}

// ---------------------------------------------------------------- pack int32 mask -> bits
__global__ void pack_mask(const int* __restrict__ m, u64* __restrict__ w) {
  const int wid = threadIdx.x >> 6, lane = threadIdx.x & 63;
  const size_t base = ((size_t)blockIdx.x * 4 + wid) * 512;
#pragma unroll
  for (int i = 0; i < 8; i++) {
    int v = m[base + i * 64 + lane];
    u64 b = __ballot(v != 0);
    if (lane == 0) w[base / 64 + i] = b;
  }
}

// ---------------------------------------------------------------- 128x256 GEMM  C = A @ B^T
// BM=128, BN=256, BK=64, 512 thr = 8 waves (2 wr x 4 wc), per-wave 64x64, acc[4][4].
// LDS 144KB: 3-buffer ring, 48KB each {A:[128][128B] @0, B:[256][128B] @16384}.
// Swizzle: lds colb = logical_colb ^ ((row&7)<<4); inverse folded into global src.
// 2 phases/K-tile: ph0 {12 ds_reads (A 8 + B kk0 4) + STAGE_A(t+2) 2 GLD, BAR,
// MFMA16 kk0, BAR}; ph1 {4 ds_reads (B kk1) + STAGE_B(t+2) 4 GLD, BAR, MFMA16 kk1,
// ENDSYNC}. vmcnt(6) at tile end retires tile t+1's 6 loads, keeps t+2's 6 in
// flight. Buffer (t+2)%3 is dead (last read in tile t-1, drained by its ENDSYNC).

enum { EP_QKV = 0, EP_EXP = 2, EP_F32 = 3 };

#define GLD(gp, lp)                                                              \
  __builtin_amdgcn_global_load_lds(                                              \
      (const __attribute__((address_space(1))) void*)(const void*)(gp),          \
      (__attribute__((address_space(3))) void*)(void*)(lp), 16, 0, 0)

#define BARS()                                   \
  do {                                           \
    asm volatile("" ::: "memory");               \
    __builtin_amdgcn_s_barrier();                \
    __builtin_amdgcn_sched_barrier(0);           \
  } while (0)

#define ENDSYNC()                                          \
  do {                                                     \
    asm volatile("s_waitcnt vmcnt(6)" ::: "memory");       \
    __builtin_amdgcn_s_barrier();                          \
    __builtin_amdgcn_sched_barrier(0);                     \
  } while (0)

#define MM(m, n, av, bv) \
  acc[m][n] = __builtin_amdgcn_mfma_f32_16x16x32_bf16(av, bv, acc[m][n], 0, 0, 0)
#define MFMA16K(aa0, aa1, aa2, aa3) do {                          \
  MM(0,0,aa0,b0); MM(0,1,aa0,b1); MM(0,2,aa0,b2); MM(0,3,aa0,b3); \
  MM(1,0,aa1,b0); MM(1,1,aa1,b1); MM(1,2,aa1,b2); MM(1,3,aa1,b3); \
  MM(2,0,aa2,b0); MM(2,1,aa2,b1); MM(2,2,aa2,b2); MM(2,3,aa2,b3); \
  MM(3,0,aa3,b0); MM(3,1,aa3,b1); MM(3,2,aa3,b2); MM(3,3,aa3,b3); \
} while (0)

#define LDA_(bo, m, kk) (*(const bx8*)(aBase + (bo) + (m) * 2048 + ((kk) ? c1s : c0s)))
#define LDB_(bo, n, kk) (*(const bx8*)(bBase + (bo) + (n) * 2048 + ((kk) ? c1s : c0s)))

#define STAGE_A(kt, bo) do {                                              \
  GLD(pA + (kt),                    smem + (bo) + tid * 16);              \
  GLD(pA + (size_t)64 * K + (kt),   smem + (bo) + 8192 + tid * 16);       \
} while (0)
#define STAGE_B(kt, bo) do {                                                    \
  GLD(pB + (kt),                    smem + (bo) + 16384 + tid * 16);            \
  GLD(pB + (size_t)64 * K + (kt),   smem + (bo) + 24576 + tid * 16);            \
  GLD(pB + (size_t)128 * K + (kt),  smem + (bo) + 32768 + tid * 16);            \
  GLD(pB + (size_t)192 * K + (kt),  smem + (bo) + 40960 + tid * 16);            \
} while (0)

template <int EPI>
__global__ __launch_bounds__(512, 2) void gemm128(
    const __bf16* __restrict__ A, const __bf16* __restrict__ Bm,
    void* __restrict__ Cout, void* __restrict__ Cout2,
    const void* __restrict__ Xtra, int N, int K, long sA, long sB) {
  extern __shared__ char smem[];

  int brow, bcol, bz = 0, qrow = 0;
  bool isQ = false;
  if (EPI == EP_QKV) {
    // 768 blocks: f<256 -> Q (64 row-blocks x 4 col-blocks, rows 0-8191);
    // f>=256 -> KV (64 x 8, rows 8192-16383). XCD swizzle chunk = 96.
    int f = (blockIdx.x & 7) * 96 + (blockIdx.x >> 3);
    if (f < 256) {
      isQ = true;
      brow = (f >> 2) * 128;
      bcol = (f & 3) * 256;
      qrow = brow;
    } else {
      int g = f - 256;
      qrow = (g >> 3) * 128;
      brow = 8192 + qrow;
      bcol = (g & 7) * 256;
    }
  } else {
    // XCD-aware bijective swizzle (pow2 grids, nwg % 8 == 0)
    const unsigned gx = gridDim.x, gy = gridDim.y;
    const unsigned nwg = gx * gy * gridDim.z;
    unsigned flat = (blockIdx.z * gy + blockIdx.y) * gx + blockIdx.x;
    flat = (flat & 7) * (nwg >> 3) + (flat >> 3);
    const int lx = __builtin_ctz(gx), ly = __builtin_ctz(gy);
    brow = ((flat >> lx) & (gy - 1)) * 128;
    bcol = (flat & (gx - 1)) * 256;
    bz   = flat >> (lx + ly);
    A  += (long)bz * sA;
    Bm += (long)bz * sB;
  }

  const int tid  = threadIdx.x;
  const int wid  = tid >> 6;
  const int lane = tid & 63;
  const int wr = wid >> 2;   // 0..1 -> rows wr*64
  const int wc = wid & 3;    // 0..3 -> cols wc*64

  fx4 acc[4][4] = {};

  // staging: thread covers lds flat tid*16 per 8KB unit; inverse swizzle on global col
  const int gcol = (((tid & 7) ^ ((tid >> 3) & 7)) << 3);  // elements
  const __bf16* Bsel = (EPI == EP_QKV && !isQ) ? (Bm + (size_t)1048576) : Bm;  // WK after WQ
  const __bf16* pA = A    + (size_t)(brow + (tid >> 3)) * K + gcol;
  const __bf16* pB = Bsel + (size_t)(bcol + (tid >> 3)) * K + gcol;

  // fragment read bases (read-side swizzle)
  const int frow = lane & 15;
  const int slot = (lane >> 4) << 4;
  const int c0s  = slot ^ ((frow & 7) << 4);
  const int c1s  = (64 + slot) ^ ((frow & 7) << 4);
  const char* aBase = smem + (wr * 64 + frow) * 128;
  const char* bBase = smem + 16384 + (wc * 64 + frow) * 128;

  // ---- prologue: tiles 0 and 1 staged; vmcnt(6) = tile0 resident, tile1 in flight
  STAGE_A(0, 0);      STAGE_B(0, 0);
  STAGE_A(64, 49152); STAGE_B(64, 49152);
  ENDSYNC();

  const int nt = K >> 6;
  int cur = 0, nxt = 49152, st2 = 98304;
  bx8 a00, a01, a02, a03, a10, a11, a12, a13, b0, b1, b2, b3;

  for (int t = 0; t < nt; ++t) {
    const int k2 = (t + 2 < nt) ? (t + 2) * 64 : 0;  // junk when past end, never read

    // ---- ph0: A all 8 frags + B kk0 (12 ds_reads); stage A(t+2)
    a00 = LDA_(cur, 0, 0); a01 = LDA_(cur, 1, 0); a02 = LDA_(cur, 2, 0); a03 = LDA_(cur, 3, 0);
    a10 = LDA_(cur, 0, 1); a11 = LDA_(cur, 1, 1); a12 = LDA_(cur, 2, 1); a13 = LDA_(cur, 3, 1);
    b0 = LDB_(cur, 0, 0); b1 = LDB_(cur, 1, 0); b2 = LDB_(cur, 2, 0); b3 = LDB_(cur, 3, 0);
    STAGE_A(k2, st2);
    BARS();
    __builtin_amdgcn_s_setprio(1); MFMA16K(a00, a01, a02, a03); __builtin_amdgcn_s_setprio(0);
    BARS();
    // ---- ph1: B kk1 (4 ds_reads); stage B(t+2)
    b0 = LDB_(cur, 0, 1); b1 = LDB_(cur, 1, 1); b2 = LDB_(cur, 2, 1); b3 = LDB_(cur, 3, 1);
    STAGE_B(k2, st2);
    BARS();
    __builtin_amdgcn_s_setprio(1); MFMA16K(a10, a11, a12, a13); __builtin_amdgcn_s_setprio(0);
    ENDSYNC();  // retires tile t+1's 6 loads; keeps tile t+2's 6 in flight

    int tmp = cur; cur = nxt; nxt = st2; st2 = tmp;
  }

  // ---- epilogue: C/D layout col = lane&15, row = (lane>>4)*4 + j  [verified m89]
  const int r0 = wr * 64 + (lane >> 4) * 4;
  const int c0 = wc * 64 + (lane & 15);

  if (EPI == EP_QKV) {
    if (isQ) {
      __bf16* Cq = (__bf16*)Cout;
#pragma unroll
      for (int m = 0; m < 4; m++) {
        int row = qrow + r0 + m * 16;
#pragma unroll
        for (int n = 0; n < 4; n++) {
          int col = bcol + c0 + n * 16;
#pragma unroll
          for (int j = 0; j < 4; j++)
            Cq[(size_t)(row + j) * 1024 + col] = (__bf16)acc[m][n][j];
        }
      }
    } else if (bcol < 1024) {
      __bf16* Ck = (__bf16*)Cout2;
#pragma unroll
      for (int m = 0; m < 4; m++) {
        int rr = qrow + r0 + m * 16;
#pragma unroll
        for (int n = 0; n < 4; n++) {
          int col = bcol + c0 + n * 16;
#pragma unroll
          for (int j = 0; j < 4; j++)
            Ck[(size_t)(rr + j) * 1024 + col] = (__bf16)acc[m][n][j];
        }
      }
    } else {
      __bf16* Cv = (__bf16*)Xtra;
#pragma unroll
      for (int m = 0; m < 4; m++) {
        int rr = qrow + r0 + m * 16;
        size_t bb = (size_t)(rr >> 11) << 21;  // batch * DH*S
        int sidx = rr & 2047;
#pragma unroll
        for (int n = 0; n < 4; n++) {
          int col = bcol + c0 + n * 16 - 1024;
          bx4 tv;
#pragma unroll
          for (int j = 0; j < 4; j++) tv[j] = (__bf16)acc[m][n][j];
          *(bx4*)&Cv[bb + (size_t)col * S_ + sidx] = tv;
        }
      }
    }
  } else if (EPI == EP_EXP) {
    __bf16* C     = (__bf16*)Cout + (size_t)bz * ((size_t)S_ * S_);
    const u64* Wm = (const u64*)Xtra + (((size_t)bz * S_ * S_) >> 6);
#pragma unroll
    for (int m = 0; m < 4; m++) {
      int row = brow + r0 + m * 16;
#pragma unroll
      for (int n = 0; n < 4; n++) {
        int col = bcol + c0 + n * 16;
#pragma unroll
        for (int j = 0; j < 4; j++) {
          size_t idx = (size_t)(row + j) * S_ + col;
          bool mk = (Wm[idx >> 6] >> (idx & 63)) & 1;
          float p = mk ? 1.0f : __expf(acc[m][n][j] * 0.03125f);  // 1/sqrt(1024)
          C[idx] = (__bf16)p;
        }
      }
    }
  } else {  // EP_F32
    float* C = (float*)Cout + (size_t)bz * ((size_t)S_ * DH);
#pragma unroll
    for (int m = 0; m < 4; m++) {
      int row = brow + r0 + m * 16;
#pragma unroll
      for (int n = 0; n < 4; n++) {
        int col = bcol + c0 + n * 16;
#pragma unroll
        for (int j = 0; j < 4; j++)
          C[(size_t)(row + j) * N + col] = acc[m][n][j];
      }
    }
  }
}

// ---------------------------------------------------------------- column sums of Pu
__global__ void colsum_partial(const __bf16* __restrict__ Pu, float* __restrict__ cs) {
  int b  = blockIdx.z;
  int k  = blockIdx.x * 256 + threadIdx.x;
  int q0 = blockIdx.y * 256;
  const __bf16* P = Pu + (size_t)b * S_ * S_ + (size_t)q0 * S_ + k;
  float s = 0.f;
#pragma unroll 8
  for (int q = 0; q < 256; q++) s += (float)P[(size_t)q * S_];
  atomicAdd(&cs[b * S_ + k], s);
}

// ---------------------------------------------------------------- vT[b][h][k] /= colsum[b][k]
__global__ void scale_vt(__bf16* __restrict__ vT, const float* __restrict__ cs) {
  size_t i = (size_t)blockIdx.x * blockDim.x + threadIdx.x;
  size_t e = i * 8;
  int b = (int)(e >> 21);      // DH*S = 2^21 elems per batch
  int k = (int)(e & (S_ - 1)); // contiguous along k
  bx8 v = ((bx8*)vT)[i];
  const float* c = cs + (size_t)b * S_ + k;
#pragma unroll
  for (int j = 0; j < 8; j++) v[j] = (__bf16)((float)v[j] / c[j]);
  ((bx8*)vT)[i] = v;
}

// ---------------------------------------------------------------- launch
extern "C" void kernel_launch(void* const* d_in, const int* in_sizes, int n_in,
                              void* d_out, int out_size, void* d_ws, size_t ws_size,
                              hipStream_t stream) {
  const float* seq1 = (const float*)d_in[0];
  const float* seq2 = (const float*)d_in[1];
  const int*   mask = (const int*)d_in[2];
  const float* Wq   = (const float*)d_in[3];
  const float* Wk   = (const float*)d_in[4];
  const float* Wv   = (const float*)d_in[5];

  char* ws = (char*)d_ws;
  __bf16* A1  = (__bf16*)(ws + WS_A1);   // stacked [seq1;seq2] 16384x1024
  __bf16* A2  = (__bf16*)(ws + WS_A2);
  __bf16* Pu  = (__bf16*)(ws + WS_PU);
  __bf16* WQb = (__bf16*)(ws + WS_WQ);   // WQ,WK,WV contiguous 3072x1024
  u64*    bm  = (u64*)(ws + WS_BM);
  __bf16* qb  = (__bf16*)(ws + WS_Q);
  __bf16* kb  = (__bf16*)(ws + WS_K);
  __bf16* vTb = (__bf16*)(ws + WS_VT);
  float*  cs  = (float*)(ws + WS_CS);

  (void)hipFuncSetAttribute((const void*)gemm128<EP_QKV>,
      hipFuncAttributeMaxDynamicSharedMemorySize, 147456);
  (void)hipFuncSetAttribute((const void*)gemm128<EP_EXP>,
      hipFuncAttributeMaxDynamicSharedMemorySize, 147456);
  (void)hipFuncSetAttribute((const void*)gemm128<EP_F32>,
      hipFuncAttributeMaxDynamicSharedMemorySize, 147456);

  // fp32 -> bf16 conversions
  cvt_seq<<<dim3(4096, 2, 1), 256, 0, stream>>>(seq1, seq2, A1, A2);
  cvt_w<<<dim3(512, 3, 1), 256, 0, stream>>>(Wq, Wk, Wv, WQb);
  // pack mask to bits
  pack_mask<<<8192, 256, 0, stream>>>(mask, bm);
  hipMemsetAsync(ws + WS_CS, 0, (size_t)B_ * S_ * sizeof(float), stream);

  // fused q/k/vT projections: 768 balanced blocks over stacked A
  gemm128<EP_QKV><<<768, 512, 147456, stream>>>(
      A1, WQb, qb, kb, vTb, 0, DIN, 0, 0);

  // Pu[b,q,k] = mask ? 1 : exp(q.k/32)   (overwrites A1/A2, dead now) — 512 blocks
  gemm128<EP_EXP><<<dim3(S_ / 256, S_ / 128, B_), 512, 147456, stream>>>(
      qb, kb, Pu, nullptr, bm, S_, DH, (long)S_ * DH, (long)S_ * DH);

  // column sums over q, then fold 1/colsum into vT
  colsum_partial<<<dim3(S_ / 256, S_ / 256, B_), 256, 0, stream>>>(Pu, cs);
  scale_vt<<<(B_ * DH * S_ / 8) / 256, 256, 0, stream>>>(vTb, cs);

  // out[b,q,h] = sum_k Pu[b,q,k] * vT'[b,h,k]  — 256 blocks, full machine
  gemm128<EP_F32><<<dim3(DH / 256, S_ / 128, B_), 512, 147456, stream>>>(
      Pu, vTb, (float*)d_out, nullptr, nullptr, DH, S_, (long)S_ * S_, (long)DH * S_);
}

// Round 8
// 194.455 us; speedup vs baseline: 1.3967x; 1.0746x over previous
//
#include <hip/hip_runtime.h>

typedef __bf16 bx8 __attribute__((ext_vector_type(8)));
typedef __bf16 bx4 __attribute__((ext_vector_type(4)));
typedef float  fx4 __attribute__((ext_vector_type(4)));
typedef unsigned long long u64;

#define B_   4
#define S_   2048
#define DIN  1024
#define DH   1024

#define MB ((size_t)1 << 20)
// workspace layout (bytes)
#define WS_A1 ((size_t)0)          // seq1 bf16, 16MB  (stacked with A2; aliased by Pu later)
#define WS_A2 ((size_t)16*MB)      // seq2 bf16, 16MB  (A1..A2 contiguous = 16384x1024)
#define WS_PU ((size_t)0)          // exp-scores bf16, 32MB (after QKV done)
#define WS_WQ ((size_t)32*MB)      // WQ,WK,WV bf16 contiguous 3072x1024 (6MB)
#define WS_BM ((size_t)38*MB)      // mask bitmask 2MB
#define WS_Q  ((size_t)40*MB)      // q bf16 [B*S, DH] 16MB
#define WS_K  ((size_t)56*MB)      // k bf16 [B*S, DH] 16MB
#define WS_VT ((size_t)72*MB)      // v^T bf16 [B, DH, S] 16MB
#define WS_CS ((size_t)88*MB)      // colsum fp32 [B, S] 32KB

// ---------------------------------------------------------------- cvt f32->bf16
__global__ void cvt_seq(const float* __restrict__ s1, const float* __restrict__ s2,
                        __bf16* __restrict__ o1, __bf16* __restrict__ o2) {
  const float* in  = blockIdx.y ? s2 : s1;
  __bf16*      out = blockIdx.y ? o2 : o1;
  size_t i = (size_t)blockIdx.x * blockDim.x + threadIdx.x;
  fx4 lo = ((const fx4*)in)[2 * i];
  fx4 hi = ((const fx4*)in)[2 * i + 1];
  bx8 o;
#pragma unroll
  for (int j = 0; j < 4; j++) { o[j] = (__bf16)lo[j]; o[j + 4] = (__bf16)hi[j]; }
  ((bx8*)out)[i] = o;
}
__global__ void cvt_w(const float* __restrict__ wq, const float* __restrict__ wk,
                      const float* __restrict__ wv, __bf16* __restrict__ oq) {
  const float* in = blockIdx.y == 0 ? wq : (blockIdx.y == 1 ? wk : wv);
  __bf16* out = oq + (size_t)blockIdx.y * (DH * DIN);
  size_t i = (size_t)blockIdx.x * blockDim.x + threadIdx.x;
  fx4 lo = ((const fx4*)in)[2 * i];
  fx4 hi = ((const fx4*)in)[2 * i + 1];
  bx8 o;
#pragma unroll
  for (int j = 0; j < 4; j++) { o[j] = (__bf16)lo[j]; o[j + 4] = (__bf16)hi[j]; }
  ((bx8*)out)[i] = o;
}

// ---------------------------------------------------------------- pack int32 mask -> bits
__global__ void pack_mask(const int* __restrict__ m, u64* __restrict__ w) {
  const int wid = threadIdx.x >> 6, lane = threadIdx.x & 63;
  const size_t base = ((size_t)blockIdx.x * 4 + wid) * 512;
#pragma unroll
  for (int i = 0; i < 8; i++) {
    int v = m[base + i * 64 + lane];
    u64 b = __ballot(v != 0);
    if (lane == 0) w[base / 64 + i] = b;
  }
}

// ---------------------------------------------------------------- 128x128 GEMM  C = A @ B^T
// BM=BN=128, BK=64, 512 thr = 8 waves (2 wr x 4 wc), per-wave 64x32, acc[4][2].
// LDS 64KB total -> 2 blocks/CU (the m97/m114 occupancy-overlap mechanism):
// 2 buffers x 32KB {A:[128][128B] @0, B:[128][128B] @16384}.
// Swizzle: lds colb = logical_colb ^ ((row&7)<<4); inverse folded into global src.
// Per K-tile: 12 ds_read_b128 + 16 MFMA + 4 GLD (stage t+1 -> nb), ONE
// vmcnt(0)+barrier at tile end (per-wave vmcnt then barrier => all GLDs landed).
// No phase barriers, no sched_barrier: compiler schedules ds_read->MFMA
// fine-grained; the co-resident block overlaps the drain.

enum { EP_QKV = 0, EP_EXP = 2, EP_F32 = 3 };

#define GLD(gp, lp)                                                              \
  __builtin_amdgcn_global_load_lds(                                              \
      (const __attribute__((address_space(1))) void*)(const void*)(gp),          \
      (__attribute__((address_space(3))) void*)(void*)(lp), 16, 0, 0)

#define ENDSYNC()                                          \
  do {                                                     \
    asm volatile("s_waitcnt vmcnt(0)" ::: "memory");       \
    __builtin_amdgcn_s_barrier();                          \
    __builtin_amdgcn_sched_barrier(0);                     \
  } while (0)

#define MM(m, n, av, bv) \
  acc[m][n] = __builtin_amdgcn_mfma_f32_16x16x32_bf16(av, bv, acc[m][n], 0, 0, 0)

#define LDA_(bo, m, kk) (*(const bx8*)(aBase + (bo) + (m) * 2048 + ((kk) ? c1s : c0s)))
#define LDB_(bo, n, kk) (*(const bx8*)(bBase + (bo) + (n) * 2048 + ((kk) ? c1s : c0s)))

#define STAGE_A(kt, bo) do {                                              \
  GLD(pA + (kt),                    smem + (bo) + tid * 16);              \
  GLD(pA + (size_t)64 * K + (kt),   smem + (bo) + 8192 + tid * 16);       \
} while (0)
#define STAGE_B(kt, bo) do {                                              \
  GLD(pB + (kt),                    smem + (bo) + 16384 + tid * 16);      \
  GLD(pB + (size_t)64 * K + (kt),   smem + (bo) + 24576 + tid * 16);      \
} while (0)

template <int EPI>
__global__ __launch_bounds__(512, 4) void gemm128(
    const __bf16* __restrict__ A, const __bf16* __restrict__ Bm,
    void* __restrict__ Cout, void* __restrict__ Cout2,
    const void* __restrict__ Xtra, int N, int K, long sA, long sB) {
  extern __shared__ char smem[];

  int brow, bcol, bz = 0, qrow = 0;
  bool isQ = false;
  if (EPI == EP_QKV) {
    // 1536 blocks: f<512 -> Q (64 row-blocks x 8 col-blocks, rows 0-8191);
    // f>=512 -> KV (64 x 16, rows 8192-16383). XCD swizzle chunk = 192.
    int f = (blockIdx.x & 7) * 192 + (blockIdx.x >> 3);
    if (f < 512) {
      isQ = true;
      qrow = (f >> 3) * 128;
      brow = qrow;
      bcol = (f & 7) * 128;
    } else {
      int g = f - 512;
      qrow = (g >> 4) * 128;
      brow = 8192 + qrow;
      bcol = (g & 15) * 128;
    }
  } else {
    // XCD-aware bijective swizzle (pow2 grids, nwg % 8 == 0)
    const unsigned gx = gridDim.x, gy = gridDim.y;
    const unsigned nwg = gx * gy * gridDim.z;
    unsigned flat = (blockIdx.z * gy + blockIdx.y) * gx + blockIdx.x;
    flat = (flat & 7) * (nwg >> 3) + (flat >> 3);
    const int lx = __builtin_ctz(gx), ly = __builtin_ctz(gy);
    brow = ((flat >> lx) & (gy - 1)) * 128;
    bcol = (flat & (gx - 1)) * 128;
    bz   = flat >> (lx + ly);
    A  += (long)bz * sA;
    Bm += (long)bz * sB;
  }

  const int tid  = threadIdx.x;
  const int wid  = tid >> 6;
  const int lane = tid & 63;
  const int wr = wid >> 2;   // 0..1 -> rows wr*64
  const int wc = wid & 3;    // 0..3 -> cols wc*32

  fx4 acc[4][2] = {};

  // staging: thread covers lds flat tid*16 per 8KB unit; inverse swizzle on global col
  const int gcol = (((tid & 7) ^ ((tid >> 3) & 7)) << 3);  // elements
  const __bf16* Bsel = (EPI == EP_QKV && !isQ) ? (Bm + (size_t)1048576) : Bm;  // WK after WQ
  const __bf16* pA = A    + (size_t)(brow + (tid >> 3)) * K + gcol;
  const __bf16* pB = Bsel + (size_t)(bcol + (tid >> 3)) * K + gcol;

  // fragment read bases (read-side swizzle)
  const int frow = lane & 15;
  const int slot = (lane >> 4) << 4;
  const int c0s  = slot ^ ((frow & 7) << 4);
  const int c1s  = (64 + slot) ^ ((frow & 7) << 4);
  const char* aBase = smem + (wr * 64 + frow) * 128;
  const char* bBase = smem + 16384 + (wc * 32 + frow) * 128;

  // ---- prologue: stage tile0 into buf0
  STAGE_A(0, 0); STAGE_B(0, 0);
  ENDSYNC();

  const int nt = K >> 6;
  int cur = 0, nb = 32768;
  bx8 a00, a01, a02, a03, a10, a11, a12, a13, b00, b01, b10, b11;

  for (int t = 0; t < nt; ++t) {
    const int k1 = (t + 1 < nt) ? (t + 1) * 64 : 0;  // junk when past end, never read

    a00 = LDA_(cur, 0, 0); a01 = LDA_(cur, 1, 0); a02 = LDA_(cur, 2, 0); a03 = LDA_(cur, 3, 0);
    b00 = LDB_(cur, 0, 0); b01 = LDB_(cur, 1, 0);
    a10 = LDA_(cur, 0, 1); a11 = LDA_(cur, 1, 1); a12 = LDA_(cur, 2, 1); a13 = LDA_(cur, 3, 1);
    b10 = LDB_(cur, 0, 1); b11 = LDB_(cur, 1, 1);
    STAGE_A(k1, nb); STAGE_B(k1, nb);

    __builtin_amdgcn_s_setprio(1);
    MM(0, 0, a00, b00); MM(0, 1, a00, b01);
    MM(1, 0, a01, b00); MM(1, 1, a01, b01);
    MM(2, 0, a02, b00); MM(2, 1, a02, b01);
    MM(3, 0, a03, b00); MM(3, 1, a03, b01);
    MM(0, 0, a10, b10); MM(0, 1, a10, b11);
    MM(1, 0, a11, b10); MM(1, 1, a11, b11);
    MM(2, 0, a12, b10); MM(2, 1, a12, b11);
    MM(3, 0, a13, b10); MM(3, 1, a13, b11);
    __builtin_amdgcn_s_setprio(0);

    ENDSYNC();  // all waves' GLDs for tile t+1 landed; safe to read nb next iter
    int tmp = cur; cur = nb; nb = tmp;
  }

  // ---- epilogue: C/D layout col = lane&15, row = (lane>>4)*4 + j  [verified m89]
  const int r0 = wr * 64 + (lane >> 4) * 4;
  const int c0 = wc * 32 + (lane & 15);

  if (EPI == EP_QKV) {
    if (isQ) {
      __bf16* Cq = (__bf16*)Cout;
#pragma unroll
      for (int m = 0; m < 4; m++) {
        int row = qrow + r0 + m * 16;
#pragma unroll
        for (int n = 0; n < 2; n++) {
          int col = bcol + c0 + n * 16;
#pragma unroll
          for (int j = 0; j < 4; j++)
            Cq[(size_t)(row + j) * 1024 + col] = (__bf16)acc[m][n][j];
        }
      }
    } else if (bcol < 1024) {
      __bf16* Ck = (__bf16*)Cout2;
#pragma unroll
      for (int m = 0; m < 4; m++) {
        int rr = qrow + r0 + m * 16;
#pragma unroll
        for (int n = 0; n < 2; n++) {
          int col = bcol + c0 + n * 16;
#pragma unroll
          for (int j = 0; j < 4; j++)
            Ck[(size_t)(rr + j) * 1024 + col] = (__bf16)acc[m][n][j];
        }
      }
    } else {
      __bf16* Cv = (__bf16*)Xtra;
#pragma unroll
      for (int m = 0; m < 4; m++) {
        int rr = qrow + r0 + m * 16;
        size_t bb = (size_t)(rr >> 11) << 21;  // batch * DH*S
        int sidx = rr & 2047;
#pragma unroll
        for (int n = 0; n < 2; n++) {
          int col = bcol + c0 + n * 16 - 1024;
          bx4 tv;
#pragma unroll
          for (int j = 0; j < 4; j++) tv[j] = (__bf16)acc[m][n][j];
          *(bx4*)&Cv[bb + (size_t)col * S_ + sidx] = tv;
        }
      }
    }
  } else if (EPI == EP_EXP) {
    __bf16* C     = (__bf16*)Cout + (size_t)bz * ((size_t)S_ * S_);
    const u64* Wm = (const u64*)Xtra + (((size_t)bz * S_ * S_) >> 6);
#pragma unroll
    for (int m = 0; m < 4; m++) {
      int row = brow + r0 + m * 16;
#pragma unroll
      for (int n = 0; n < 2; n++) {
        int col = bcol + c0 + n * 16;
#pragma unroll
        for (int j = 0; j < 4; j++) {
          size_t idx = (size_t)(row + j) * S_ + col;
          bool mk = (Wm[idx >> 6] >> (idx & 63)) & 1;
          float p = mk ? 1.0f : __expf(acc[m][n][j] * 0.03125f);  // 1/sqrt(1024)
          C[idx] = (__bf16)p;
        }
      }
    }
  } else {  // EP_F32
    float* C = (float*)Cout + (size_t)bz * ((size_t)S_ * DH);
#pragma unroll
    for (int m = 0; m < 4; m++) {
      int row = brow + r0 + m * 16;
#pragma unroll
      for (int n = 0; n < 2; n++) {
        int col = bcol + c0 + n * 16;
#pragma unroll
        for (int j = 0; j < 4; j++)
          C[(size_t)(row + j) * N + col] = acc[m][n][j];
      }
    }
  }
}

// ---------------------------------------------------------------- column sums of Pu
__global__ void colsum_partial(const __bf16* __restrict__ Pu, float* __restrict__ cs) {
  int b  = blockIdx.z;
  int k  = blockIdx.x * 256 + threadIdx.x;
  int q0 = blockIdx.y * 256;
  const __bf16* P = Pu + (size_t)b * S_ * S_ + (size_t)q0 * S_ + k;
  float s = 0.f;
#pragma unroll 8
  for (int q = 0; q < 256; q++) s += (float)P[(size_t)q * S_];
  atomicAdd(&cs[b * S_ + k], s);
}

// ---------------------------------------------------------------- vT[b][h][k] /= colsum[b][k]
__global__ void scale_vt(__bf16* __restrict__ vT, const float* __restrict__ cs) {
  size_t i = (size_t)blockIdx.x * blockDim.x + threadIdx.x;
  size_t e = i * 8;
  int b = (int)(e >> 21);      // DH*S = 2^21 elems per batch
  int k = (int)(e & (S_ - 1)); // contiguous along k
  bx8 v = ((bx8*)vT)[i];
  const float* c = cs + (size_t)b * S_ + k;
#pragma unroll
  for (int j = 0; j < 8; j++) v[j] = (__bf16)((float)v[j] / c[j]);
  ((bx8*)vT)[i] = v;
}

// ---------------------------------------------------------------- launch
extern "C" void kernel_launch(void* const* d_in, const int* in_sizes, int n_in,
                              void* d_out, int out_size, void* d_ws, size_t ws_size,
                              hipStream_t stream) {
  const float* seq1 = (const float*)d_in[0];
  const float* seq2 = (const float*)d_in[1];
  const int*   mask = (const int*)d_in[2];
  const float* Wq   = (const float*)d_in[3];
  const float* Wk   = (const float*)d_in[4];
  const float* Wv   = (const float*)d_in[5];

  char* ws = (char*)d_ws;
  __bf16* A1  = (__bf16*)(ws + WS_A1);   // stacked [seq1;seq2] 16384x1024
  __bf16* A2  = (__bf16*)(ws + WS_A2);
  __bf16* Pu  = (__bf16*)(ws + WS_PU);
  __bf16* WQb = (__bf16*)(ws + WS_WQ);   // WQ,WK,WV contiguous 3072x1024
  u64*    bm  = (u64*)(ws + WS_BM);
  __bf16* qb  = (__bf16*)(ws + WS_Q);
  __bf16* kb  = (__bf16*)(ws + WS_K);
  __bf16* vTb = (__bf16*)(ws + WS_VT);
  float*  cs  = (float*)(ws + WS_CS);

  (void)hipFuncSetAttribute((const void*)gemm128<EP_QKV>,
      hipFuncAttributeMaxDynamicSharedMemorySize, 65536);
  (void)hipFuncSetAttribute((const void*)gemm128<EP_EXP>,
      hipFuncAttributeMaxDynamicSharedMemorySize, 65536);
  (void)hipFuncSetAttribute((const void*)gemm128<EP_F32>,
      hipFuncAttributeMaxDynamicSharedMemorySize, 65536);

  // fp32 -> bf16 conversions
  cvt_seq<<<dim3(4096, 2, 1), 256, 0, stream>>>(seq1, seq2, A1, A2);
  cvt_w<<<dim3(512, 3, 1), 256, 0, stream>>>(Wq, Wk, Wv, WQb);
  // pack mask to bits
  pack_mask<<<8192, 256, 0, stream>>>(mask, bm);
  hipMemsetAsync(ws + WS_CS, 0, (size_t)B_ * S_ * sizeof(float), stream);

  // fused q/k/vT projections: 1536 balanced blocks (3 rounds at 2 blocks/CU)
  gemm128<EP_QKV><<<1536, 512, 65536, stream>>>(
      A1, WQb, qb, kb, vTb, 0, DIN, 0, 0);

  // Pu[b,q,k] = mask ? 1 : exp(q.k/32)  — 1024 blocks (2 rounds)
  gemm128<EP_EXP><<<dim3(S_ / 128, S_ / 128, B_), 512, 65536, stream>>>(
      qb, kb, Pu, nullptr, bm, S_, DH, (long)S_ * DH, (long)S_ * DH);

  // column sums over q, then fold 1/colsum into vT
  colsum_partial<<<dim3(S_ / 256, S_ / 256, B_), 256, 0, stream>>>(Pu, cs);
  scale_vt<<<(B_ * DH * S_ / 8) / 256, 256, 0, stream>>>(vTb, cs);

  // out[b,q,h] = sum_k Pu[b,q,k] * vT'[b,h,k]  — 512 blocks (1 round)
  gemm128<EP_F32><<<dim3(DH / 128, S_ / 128, B_), 512, 65536, stream>>>(
      Pu, vTb, (float*)d_out, nullptr, nullptr, DH, S_, (long)S_ * S_, (long)DH * S_);
}

// Round 9
// 178.900 us; speedup vs baseline: 1.5182x; 1.0869x over previous
//
#include <hip/hip_runtime.h>

typedef __bf16 bx8 __attribute__((ext_vector_type(8)));
typedef __bf16 bx4 __attribute__((ext_vector_type(4)));
typedef float  fx4 __attribute__((ext_vector_type(4)));
typedef unsigned long long u64;

#define B_   4
#define S_   2048
#define DIN  1024
#define DH   1024

#define MB ((size_t)1 << 20)
// workspace layout (bytes)
#define WS_A1 ((size_t)0)          // seq1 bf16, 16MB  (stacked with A2; aliased by Pu later)
#define WS_A2 ((size_t)16*MB)      // seq2 bf16, 16MB  (A1..A2 contiguous = 16384x1024)
#define WS_PU ((size_t)0)          // exp-scores bf16, 32MB (after QKV done)
#define WS_WQ ((size_t)32*MB)      // WQ,WK,WV bf16 contiguous 3072x1024 (6MB)
#define WS_BM ((size_t)38*MB)      // mask bitmask 2MB
#define WS_Q  ((size_t)40*MB)      // q bf16 [B*S, DH] 16MB
#define WS_K  ((size_t)56*MB)      // k bf16 [B*S, DH] 16MB
#define WS_VT ((size_t)72*MB)      // v^T bf16 [B, DH, S] 16MB
#define WS_CS ((size_t)88*MB)      // colsum fp32 [B, S] 32KB

// ---------------------------------------------------------------- cvt f32->bf16
__global__ void cvt_seq(const float* __restrict__ s1, const float* __restrict__ s2,
                        __bf16* __restrict__ o1, __bf16* __restrict__ o2) {
  const float* in  = blockIdx.y ? s2 : s1;
  __bf16*      out = blockIdx.y ? o2 : o1;
  size_t i = (size_t)blockIdx.x * blockDim.x + threadIdx.x;
  fx4 lo = ((const fx4*)in)[2 * i];
  fx4 hi = ((const fx4*)in)[2 * i + 1];
  bx8 o;
#pragma unroll
  for (int j = 0; j < 4; j++) { o[j] = (__bf16)lo[j]; o[j + 4] = (__bf16)hi[j]; }
  ((bx8*)out)[i] = o;
}
__global__ void cvt_w(const float* __restrict__ wq, const float* __restrict__ wk,
                      const float* __restrict__ wv, __bf16* __restrict__ oq) {
  const float* in = blockIdx.y == 0 ? wq : (blockIdx.y == 1 ? wk : wv);
  __bf16* out = oq + (size_t)blockIdx.y * (DH * DIN);
  size_t i = (size_t)blockIdx.x * blockDim.x + threadIdx.x;
  fx4 lo = ((const fx4*)in)[2 * i];
  fx4 hi = ((const fx4*)in)[2 * i + 1];
  bx8 o;
#pragma unroll
  for (int j = 0; j < 4; j++) { o[j] = (__bf16)lo[j]; o[j + 4] = (__bf16)hi[j]; }
  ((bx8*)out)[i] = o;
}

// ---------------------------------------------------------------- pack int32 mask -> bits
__global__ void pack_mask(const int* __restrict__ m, u64* __restrict__ w) {
  const int wid = threadIdx.x >> 6, lane = threadIdx.x & 63;
  const size_t base = ((size_t)blockIdx.x * 4 + wid) * 512;
#pragma unroll
  for (int i = 0; i < 8; i++) {
    int v = m[base + i * 64 + lane];
    u64 b = __ballot(v != 0);
    if (lane == 0) w[base / 64 + i] = b;
  }
}

// ---------------------------------------------------------------- 128x128 GEMM  C = A @ B^T
// BM=BN=128, BK=64, 512 thr = 8 waves (2 wr x 4 wc), per-wave 64x32, acc[4][2].
// LDS 64KB total -> 2 blocks/CU (m97/m114 occupancy-overlap mechanism):
// 2 buffers x 32KB {A:[128][128B] @0, B:[128][128B] @16384}.
// Swizzle: lds colb = logical_colb ^ ((row&7)<<4); inverse folded into global src.
// Per K-tile: STAGE(t+1) issued FIRST (GLD latency hides under ds_read+MFMA),
// then 12 ds_read_b128 + 16 MFMA, ONE vmcnt(0)+barrier at tile end.
// EXP epilogue fuses the column-sum: shfl_xor(16,32) over lane-groups, then
// lanes 0-15 atomicAdd (256 atomics/block) -> removes the 32MB colsum pass.

enum { EP_QKV = 0, EP_EXP = 2, EP_F32 = 3 };

#define GLD(gp, lp)                                                              \
  __builtin_amdgcn_global_load_lds(                                              \
      (const __attribute__((address_space(1))) void*)(const void*)(gp),          \
      (__attribute__((address_space(3))) void*)(void*)(lp), 16, 0, 0)

#define ENDSYNC()                                          \
  do {                                                     \
    asm volatile("s_waitcnt vmcnt(0)" ::: "memory");       \
    __builtin_amdgcn_s_barrier();                          \
    __builtin_amdgcn_sched_barrier(0);                     \
  } while (0)

#define MM(m, n, av, bv) \
  acc[m][n] = __builtin_amdgcn_mfma_f32_16x16x32_bf16(av, bv, acc[m][n], 0, 0, 0)

#define LDA_(bo, m, kk) (*(const bx8*)(aBase + (bo) + (m) * 2048 + ((kk) ? c1s : c0s)))
#define LDB_(bo, n, kk) (*(const bx8*)(bBase + (bo) + (n) * 2048 + ((kk) ? c1s : c0s)))

#define STAGE_A(kt, bo) do {                                              \
  GLD(pA + (kt),                    smem + (bo) + tid * 16);              \
  GLD(pA + (size_t)64 * K + (kt),   smem + (bo) + 8192 + tid * 16);       \
} while (0)
#define STAGE_B(kt, bo) do {                                              \
  GLD(pB + (kt),                    smem + (bo) + 16384 + tid * 16);      \
  GLD(pB + (size_t)64 * K + (kt),   smem + (bo) + 24576 + tid * 16);      \
} while (0)

template <int EPI>
__global__ __launch_bounds__(512, 4) void gemm128(
    const __bf16* __restrict__ A, const __bf16* __restrict__ Bm,
    void* __restrict__ Cout, void* __restrict__ Cout2,
    const void* __restrict__ Xtra, int N, int K, long sA, long sB) {
  extern __shared__ char smem[];

  int brow, bcol, bz = 0, qrow = 0;
  bool isQ = false;
  if (EPI == EP_QKV) {
    // 1536 blocks: f<512 -> Q (64 row-blocks x 8 col-blocks, rows 0-8191);
    // f>=512 -> KV (64 x 16, rows 8192-16383). XCD swizzle chunk = 192.
    int f = (blockIdx.x & 7) * 192 + (blockIdx.x >> 3);
    if (f < 512) {
      isQ = true;
      qrow = (f >> 3) * 128;
      brow = qrow;
      bcol = (f & 7) * 128;
    } else {
      int g = f - 512;
      qrow = (g >> 4) * 128;
      brow = 8192 + qrow;
      bcol = (g & 15) * 128;
    }
  } else {
    // XCD-aware bijective swizzle (pow2 grids, nwg % 8 == 0)
    const unsigned gx = gridDim.x, gy = gridDim.y;
    const unsigned nwg = gx * gy * gridDim.z;
    unsigned flat = (blockIdx.z * gy + blockIdx.y) * gx + blockIdx.x;
    flat = (flat & 7) * (nwg >> 3) + (flat >> 3);
    const int lx = __builtin_ctz(gx), ly = __builtin_ctz(gy);
    brow = ((flat >> lx) & (gy - 1)) * 128;
    bcol = (flat & (gx - 1)) * 128;
    bz   = flat >> (lx + ly);
    A  += (long)bz * sA;
    Bm += (long)bz * sB;
  }

  const int tid  = threadIdx.x;
  const int wid  = tid >> 6;
  const int lane = tid & 63;
  const int wr = wid >> 2;   // 0..1 -> rows wr*64
  const int wc = wid & 3;    // 0..3 -> cols wc*32

  fx4 acc[4][2] = {};

  // staging: thread covers lds flat tid*16 per 8KB unit; inverse swizzle on global col
  const int gcol = (((tid & 7) ^ ((tid >> 3) & 7)) << 3);  // elements
  const __bf16* Bsel = (EPI == EP_QKV && !isQ) ? (Bm + (size_t)1048576) : Bm;  // WK after WQ
  const __bf16* pA = A    + (size_t)(brow + (tid >> 3)) * K + gcol;
  const __bf16* pB = Bsel + (size_t)(bcol + (tid >> 3)) * K + gcol;

  // fragment read bases (read-side swizzle)
  const int frow = lane & 15;
  const int slot = (lane >> 4) << 4;
  const int c0s  = slot ^ ((frow & 7) << 4);
  const int c1s  = (64 + slot) ^ ((frow & 7) << 4);
  const char* aBase = smem + (wr * 64 + frow) * 128;
  const char* bBase = smem + 16384 + (wc * 32 + frow) * 128;

  // ---- prologue: stage tile0 into buf0
  STAGE_A(0, 0); STAGE_B(0, 0);
  ENDSYNC();

  const int nt = K >> 6;
  int cur = 0, nb = 32768;
  bx8 a00, a01, a02, a03, a10, a11, a12, a13, b00, b01, b10, b11;

  for (int t = 0; t < nt; ++t) {
    const int k1 = (t + 1 < nt) ? (t + 1) * 64 : 0;  // junk when past end, never read

    // stage t+1 FIRST: GLD latency hides under ds_read issue + MFMA
    STAGE_A(k1, nb); STAGE_B(k1, nb);

    a00 = LDA_(cur, 0, 0); a01 = LDA_(cur, 1, 0); a02 = LDA_(cur, 2, 0); a03 = LDA_(cur, 3, 0);
    b00 = LDB_(cur, 0, 0); b01 = LDB_(cur, 1, 0);
    a10 = LDA_(cur, 0, 1); a11 = LDA_(cur, 1, 1); a12 = LDA_(cur, 2, 1); a13 = LDA_(cur, 3, 1);
    b10 = LDB_(cur, 0, 1); b11 = LDB_(cur, 1, 1);

    __builtin_amdgcn_s_setprio(1);
    MM(0, 0, a00, b00); MM(0, 1, a00, b01);
    MM(1, 0, a01, b00); MM(1, 1, a01, b01);
    MM(2, 0, a02, b00); MM(2, 1, a02, b01);
    MM(3, 0, a03, b00); MM(3, 1, a03, b01);
    MM(0, 0, a10, b10); MM(0, 1, a10, b11);
    MM(1, 0, a11, b10); MM(1, 1, a11, b11);
    MM(2, 0, a12, b10); MM(2, 1, a12, b11);
    MM(3, 0, a13, b10); MM(3, 1, a13, b11);
    __builtin_amdgcn_s_setprio(0);

    ENDSYNC();  // all waves' GLDs for tile t+1 landed; safe to read nb next iter
    int tmp = cur; cur = nb; nb = tmp;
  }

  // ---- epilogue: C/D layout col = lane&15, row = (lane>>4)*4 + j  [verified m89]
  const int r0 = wr * 64 + (lane >> 4) * 4;
  const int c0 = wc * 32 + (lane & 15);

  if (EPI == EP_QKV) {
    if (isQ) {
      __bf16* Cq = (__bf16*)Cout;
#pragma unroll
      for (int m = 0; m < 4; m++) {
        int row = qrow + r0 + m * 16;
#pragma unroll
        for (int n = 0; n < 2; n++) {
          int col = bcol + c0 + n * 16;
#pragma unroll
          for (int j = 0; j < 4; j++)
            Cq[(size_t)(row + j) * 1024 + col] = (__bf16)acc[m][n][j];
        }
      }
    } else if (bcol < 1024) {
      __bf16* Ck = (__bf16*)Cout2;
#pragma unroll
      for (int m = 0; m < 4; m++) {
        int rr = qrow + r0 + m * 16;
#pragma unroll
        for (int n = 0; n < 2; n++) {
          int col = bcol + c0 + n * 16;
#pragma unroll
          for (int j = 0; j < 4; j++)
            Ck[(size_t)(rr + j) * 1024 + col] = (__bf16)acc[m][n][j];
        }
      }
    } else {
      __bf16* Cv = (__bf16*)Xtra;
#pragma unroll
      for (int m = 0; m < 4; m++) {
        int rr = qrow + r0 + m * 16;
        size_t bb = (size_t)(rr >> 11) << 21;  // batch * DH*S
        int sidx = rr & 2047;
#pragma unroll
        for (int n = 0; n < 2; n++) {
          int col = bcol + c0 + n * 16 - 1024;
          bx4 tv;
#pragma unroll
          for (int j = 0; j < 4; j++) tv[j] = (__bf16)acc[m][n][j];
          *(bx4*)&Cv[bb + (size_t)col * S_ + sidx] = tv;
        }
      }
    }
  } else if (EPI == EP_EXP) {
    __bf16* C     = (__bf16*)Cout + (size_t)bz * ((size_t)S_ * S_);
    const u64* Wm = (const u64*)Xtra + (((size_t)bz * S_ * S_) >> 6);
    float csum0 = 0.f, csum1 = 0.f;
#pragma unroll
    for (int m = 0; m < 4; m++) {
      int row = brow + r0 + m * 16;
#pragma unroll
      for (int n = 0; n < 2; n++) {
        int col = bcol + c0 + n * 16;
        float cl = 0.f;
#pragma unroll
        for (int j = 0; j < 4; j++) {
          size_t idx = (size_t)(row + j) * S_ + col;
          bool mk = (Wm[idx >> 6] >> (idx & 63)) & 1;
          float p = mk ? 1.0f : __expf(acc[m][n][j] * 0.03125f);  // 1/sqrt(1024)
          cl += p;
          C[idx] = (__bf16)p;
        }
        if (n == 0) csum0 += cl; else csum1 += cl;
      }
    }
    // fused column-sum: reduce over lane>>4 groups (same col, rows r0 differ)
    csum0 += __shfl_xor(csum0, 16); csum0 += __shfl_xor(csum0, 32);
    csum1 += __shfl_xor(csum1, 16); csum1 += __shfl_xor(csum1, 32);
    if (lane < 16) {
      float* csp = (float*)Cout2 + (size_t)bz * S_ + bcol + wc * 32 + lane;
      atomicAdd(csp, csum0);
      atomicAdd(csp + 16, csum1);
    }
  } else {  // EP_F32
    float* C = (float*)Cout + (size_t)bz * ((size_t)S_ * DH);
#pragma unroll
    for (int m = 0; m < 4; m++) {
      int row = brow + r0 + m * 16;
#pragma unroll
      for (int n = 0; n < 2; n++) {
        int col = bcol + c0 + n * 16;
#pragma unroll
        for (int j = 0; j < 4; j++)
          C[(size_t)(row + j) * N + col] = acc[m][n][j];
      }
    }
  }
}

// ---------------------------------------------------------------- vT[b][h][k] /= colsum[b][k]
__global__ void scale_vt(__bf16* __restrict__ vT, const float* __restrict__ cs) {
  size_t i = (size_t)blockIdx.x * blockDim.x + threadIdx.x;
  size_t e = i * 8;
  int b = (int)(e >> 21);      // DH*S = 2^21 elems per batch
  int k = (int)(e & (S_ - 1)); // contiguous along k
  bx8 v = ((bx8*)vT)[i];
  const float* c = cs + (size_t)b * S_ + k;
#pragma unroll
  for (int j = 0; j < 8; j++) v[j] = (__bf16)((float)v[j] / c[j]);
  ((bx8*)vT)[i] = v;
}

// ---------------------------------------------------------------- launch
extern "C" void kernel_launch(void* const* d_in, const int* in_sizes, int n_in,
                              void* d_out, int out_size, void* d_ws, size_t ws_size,
                              hipStream_t stream) {
  const float* seq1 = (const float*)d_in[0];
  const float* seq2 = (const float*)d_in[1];
  const int*   mask = (const int*)d_in[2];
  const float* Wq   = (const float*)d_in[3];
  const float* Wk   = (const float*)d_in[4];
  const float* Wv   = (const float*)d_in[5];

  char* ws = (char*)d_ws;
  __bf16* A1  = (__bf16*)(ws + WS_A1);   // stacked [seq1;seq2] 16384x1024
  __bf16* A2  = (__bf16*)(ws + WS_A2);
  __bf16* Pu  = (__bf16*)(ws + WS_PU);
  __bf16* WQb = (__bf16*)(ws + WS_WQ);   // WQ,WK,WV contiguous 3072x1024
  u64*    bm  = (u64*)(ws + WS_BM);
  __bf16* qb  = (__bf16*)(ws + WS_Q);
  __bf16* kb  = (__bf16*)(ws + WS_K);
  __bf16* vTb = (__bf16*)(ws + WS_VT);
  float*  cs  = (float*)(ws + WS_CS);

  (void)hipFuncSetAttribute((const void*)gemm128<EP_QKV>,
      hipFuncAttributeMaxDynamicSharedMemorySize, 65536);
  (void)hipFuncSetAttribute((const void*)gemm128<EP_EXP>,
      hipFuncAttributeMaxDynamicSharedMemorySize, 65536);
  (void)hipFuncSetAttribute((const void*)gemm128<EP_F32>,
      hipFuncAttributeMaxDynamicSharedMemorySize, 65536);

  // fp32 -> bf16 conversions
  cvt_seq<<<dim3(4096, 2, 1), 256, 0, stream>>>(seq1, seq2, A1, A2);
  cvt_w<<<dim3(512, 3, 1), 256, 0, stream>>>(Wq, Wk, Wv, WQb);
  // pack mask to bits
  pack_mask<<<8192, 256, 0, stream>>>(mask, bm);
  hipMemsetAsync(ws + WS_CS, 0, (size_t)B_ * S_ * sizeof(float), stream);

  // fused q/k/vT projections: 1536 balanced blocks (3 rounds at 2 blocks/CU)
  gemm128<EP_QKV><<<1536, 512, 65536, stream>>>(
      A1, WQb, qb, kb, vTb, 0, DIN, 0, 0);

  // Pu[b,q,k] = mask ? 1 : exp(q.k/32); fused column-sum into cs — 1024 blocks
  gemm128<EP_EXP><<<dim3(S_ / 128, S_ / 128, B_), 512, 65536, stream>>>(
      qb, kb, Pu, cs, bm, S_, DH, (long)S_ * DH, (long)S_ * DH);

  // fold 1/colsum into vT
  scale_vt<<<(B_ * DH * S_ / 8) / 256, 256, 0, stream>>>(vTb, cs);

  // out[b,q,h] = sum_k Pu[b,q,k] * vT'[b,h,k]  — 512 blocks (1 round)
  gemm128<EP_F32><<<dim3(DH / 128, S_ / 128, B_), 512, 65536, stream>>>(
      Pu, vTb, (float*)d_out, nullptr, nullptr, DH, S_, (long)S_ * S_, (long)DH * S_);
}